// Round 1
// baseline (279.456 us; speedup 1.0000x reference)
//
#include <hip/hip_runtime.h>
#include <math.h>

// ---------------- kernel 1: histogram of sample ids ----------------
__global__ __launch_bounds__(256) void k_hist(const int* __restrict__ idx,
                                              int* __restrict__ counts, int n) {
    int i = blockIdx.x * 256 + threadIdx.x;
    if (i < n) atomicAdd(&counts[idx[i]], 1);
}

// ---------------- kernel 2: exclusive prefix scan (single block, S<=8192) ---
__global__ __launch_bounds__(1024) void k_scan(const int* __restrict__ counts,
                                               int* __restrict__ base,
                                               int* __restrict__ cursor, int S) {
    __shared__ int sh[1024];
    int t = threadIdx.x;
    int loc[8];
    int sum = 0;
#pragma unroll
    for (int j = 0; j < 8; ++j) {
        int g = t * 8 + j;
        loc[j] = sum;                       // exclusive within thread
        sum += (g < S) ? counts[g] : 0;
    }
    sh[t] = sum;
    __syncthreads();
    int total = sum;
    for (int off = 1; off < 1024; off <<= 1) {
        int v = (t >= off) ? sh[t - off] : 0;
        __syncthreads();
        sh[t] += v;
        __syncthreads();
    }
    int excl = sh[t] - total;               // exclusive across threads
#pragma unroll
    for (int j = 0; j < 8; ++j) {
        int g = t * 8 + j;
        if (g < S) {
            int b = excl + loc[j];
            base[g] = b;
            cursor[g] = b;
        }
    }
}

// ---------------- kernel 3: scatter element ids grouped by sample -----------
__global__ __launch_bounds__(256) void k_scatter(const int* __restrict__ idx,
                                                 int* __restrict__ cursor,
                                                 int* __restrict__ order, int n) {
    int i = blockIdx.x * 256 + threadIdx.x;
    if (i < n) {
        int s = idx[i];
        int pos = atomicAdd(&cursor[s], 1);
        order[pos] = i;
    }
}

// ---------------- kernel 4: per-sample online softmax-pool ------------------
// One wave per sample. Half-wave processes one element: lanes 0..31 element A,
// lanes 32..63 element B. Lane owns dims 4*(lane&31)..+3 (float4).
// pooled[s] = (sum_i exp(score_i) * emb_i) / (sum_i exp(score_i))
__global__ __launch_bounds__(256, 8) void k_pool(
        const float* __restrict__ emb, const float* __restrict__ w_att,
        const int* __restrict__ base, const int* __restrict__ counts,
        const int* __restrict__ order, float* __restrict__ pooled, int S) {
    int wave = (blockIdx.x << 2) | (threadIdx.x >> 6);
    int lane = threadIdx.x & 63;
    if (wave >= S) return;
    int b   = base[wave];
    int cnt = counts[wave];
    int half = lane >> 5;                   // 0: element e, 1: element e+1
    int l32  = lane & 31;
    float4 wa = *reinterpret_cast<const float4*>(w_att + 4 * l32);
    float4 acc = make_float4(0.f, 0.f, 0.f, 0.f);
    float Z = 0.f;
    for (int e = 0; e < cnt; e += 2) {
        int sub = e + half;
        bool valid = sub < cnt;
        int sidx = valid ? sub : (cnt - 1);
        int i = order[b + sidx];
        const float4 v = *reinterpret_cast<const float4*>(emb + (size_t)i * 128 + 4 * l32);
        float part = v.x * wa.x + v.y * wa.y + v.z * wa.z + v.w * wa.w;
        // reduce within 32-lane half (masks 1..16 stay inside the half)
#pragma unroll
        for (int m = 1; m < 32; m <<= 1) part += __shfl_xor(part, m, 64);
        float ex = valid ? __expf(part) : 0.f;
        Z += ex;
        acc.x = fmaf(ex, v.x, acc.x);
        acc.y = fmaf(ex, v.y, acc.y);
        acc.z = fmaf(ex, v.z, acc.z);
        acc.w = fmaf(ex, v.w, acc.w);
    }
    // combine the two halves (each lane pair l / l+32 holds the same dims)
    acc.x += __shfl_xor(acc.x, 32, 64);
    acc.y += __shfl_xor(acc.y, 32, 64);
    acc.z += __shfl_xor(acc.z, 32, 64);
    acc.w += __shfl_xor(acc.w, 32, 64);
    Z     += __shfl_xor(Z,     32, 64);
    float rn = (cnt > 0) ? (1.0f / Z) : 0.f;
    if (half == 0) {
        float4 o = make_float4(acc.x * rn, acc.y * rn, acc.z * rn, acc.w * rn);
        *reinterpret_cast<float4*>(pooled + (size_t)wave * 128 + 4 * l32) = o;
    }
}

// ---------------- kernel 5: projection out = pooled @ w_out^T ---------------
// In-place on d_out: every block reads ALL its pooled rows (both k-halves)
// before storing any output row, and rows are block-exclusive -> safe.
#define SPB 8   // samples per block (compile-time so acc[] stays in registers)
__global__ __launch_bounds__(256, 4) void k_proj(
        const float* __restrict__ w_out, float* __restrict__ io, int S) {
    __shared__ float wl[128][68];           // half of w_out, pad 68 (16B-aligned rows)
    __shared__ float pl[2][64];
    int t = threadIdx.x;
    int d = t & 127;
    int h = t >> 7;
    int s0 = blockIdx.x * SPB;
    float acc[SPB / 2];
#pragma unroll
    for (int j = 0; j < SPB / 2; ++j) acc[j] = 0.f;

    for (int ph = 0; ph < 2; ++ph) {
        __syncthreads();                    // prev phase's reads of wl are done
        // stage w_out[:, ph*64 .. ph*64+63]  (8192 floats = 2048 float4)
        for (int j = t; j < 2048; j += 256) {
            int r  = j >> 4;
            int c4 = j & 15;
            float4 wv = reinterpret_cast<const float4*>(w_out + (size_t)r * 128 + ph * 64)[c4];
            wl[r][c4 * 4 + 0] = wv.x;
            wl[r][c4 * 4 + 1] = wv.y;
            wl[r][c4 * 4 + 2] = wv.z;
            wl[r][c4 * 4 + 3] = wv.w;
        }
        __syncthreads();
#pragma unroll
        for (int g = 0; g < SPB; g += 2) {
            if (t < 128) {
                int hh = t >> 6, kk = t & 63;
                int ss = s0 + g + hh;
                pl[hh][kk] = (ss < S) ? io[(size_t)ss * 128 + ph * 64 + kk] : 0.f;
            }
            __syncthreads();
            float a = 0.f;
#pragma unroll
            for (int k4 = 0; k4 < 16; ++k4) {
                float4 wv = *reinterpret_cast<const float4*>(&wl[d][k4 * 4]);
                float4 pv = *reinterpret_cast<const float4*>(&pl[h][k4 * 4]);
                a = fmaf(wv.x, pv.x, a);
                a = fmaf(wv.y, pv.y, a);
                a = fmaf(wv.z, pv.z, a);
                a = fmaf(wv.w, pv.w, a);
            }
            acc[g >> 1] += a;
            __syncthreads();                // pl reused next iteration
        }
    }
    // all pooled reads done by every thread in the block -> safe to overwrite
#pragma unroll
    for (int g = 0; g < SPB; g += 2) {
        int s = s0 + g + h;
        if (s < S) io[(size_t)s * 128 + d] = acc[g >> 1];
    }
}

extern "C" void kernel_launch(void* const* d_in, const int* in_sizes, int n_in,
                              void* d_out, int out_size, void* d_ws, size_t ws_size,
                              hipStream_t stream) {
    const float* emb   = (const float*)d_in[0];
    const float* w_att = (const float*)d_in[1];
    const float* w_out = (const float*)d_in[2];
    const int*   idx   = (const int*)d_in[3];
    // d_in[4] = num_samples (device scalar) -- derive S from out_size instead
    const int N = in_sizes[0] / 128;
    const int S = out_size / 128;

    char* ws = (char*)d_ws;
    int* counts = (int*)(ws + 0);
    int* base   = (int*)(ws + 32 * 1024);
    int* cursor = (int*)(ws + 64 * 1024);
    int* order  = (int*)(ws + 128 * 1024);      // N ints
    float* out  = (float*)d_out;                // also holds pooled temporarily

    hipMemsetAsync(counts, 0, (size_t)S * sizeof(int), stream);
    k_hist   <<<(N + 255) / 256, 256, 0, stream>>>(idx, counts, N);
    k_scan   <<<1, 1024, 0, stream>>>(counts, base, cursor, S);
    k_scatter<<<(N + 255) / 256, 256, 0, stream>>>(idx, cursor, order, N);
    k_pool   <<<(S + 3) / 4, 256, 0, stream>>>(emb, w_att, base, counts, order, out, S);
    k_proj   <<<(S + SPB - 1) / SPB, 256, 0, stream>>>(w_out, out, S);
}

// Round 2
// 261.817 us; speedup vs baseline: 1.0674x; 1.0674x over previous
//
#include <hip/hip_runtime.h>
#include <math.h>

// ---------------- kernel 1: histogram of sample ids ----------------
__global__ __launch_bounds__(256) void k_hist(const int* __restrict__ idx,
                                              int* __restrict__ counts, int n) {
    int i = blockIdx.x * 256 + threadIdx.x;
    if (i < n) atomicAdd(&counts[idx[i]], 1);
}

// ---------------- kernel 2: exclusive prefix scan (single block, S<=8192) ---
__global__ __launch_bounds__(1024) void k_scan(const int* __restrict__ counts,
                                               int* __restrict__ base,
                                               int* __restrict__ cursor, int S) {
    __shared__ int sh[1024];
    int t = threadIdx.x;
    int loc[8];
    int sum = 0;
#pragma unroll
    for (int j = 0; j < 8; ++j) {
        int g = t * 8 + j;
        loc[j] = sum;                       // exclusive within thread
        sum += (g < S) ? counts[g] : 0;
    }
    sh[t] = sum;
    __syncthreads();
    int total = sum;
    for (int off = 1; off < 1024; off <<= 1) {
        int v = (t >= off) ? sh[t - off] : 0;
        __syncthreads();
        sh[t] += v;
        __syncthreads();
    }
    int excl = sh[t] - total;               // exclusive across threads
#pragma unroll
    for (int j = 0; j < 8; ++j) {
        int g = t * 8 + j;
        if (g < S) {
            int b = excl + loc[j];
            base[g] = b;
            cursor[g] = b;
        }
    }
}

// ---------------- kernel 3: scatter element ids grouped by sample -----------
__global__ __launch_bounds__(256) void k_scatter(const int* __restrict__ idx,
                                                 int* __restrict__ cursor,
                                                 int* __restrict__ order, int n) {
    int i = blockIdx.x * 256 + threadIdx.x;
    if (i < n) {
        int s = idx[i];
        int pos = atomicAdd(&cursor[s], 1);
        order[pos] = i;
    }
}

// ---------------- kernel 4: per-sample online softmax-pool ------------------
// One wave per sample. 4 groups of 16 lanes; group g handles element e+g.
// Lane owns dims 8*(lane&15) .. +7 (two float4). One-iteration-ahead prefetch
// of the next 4 rows hides HBM gather latency behind the current compute.
// pooled[s] = (sum_i exp(score_i) * emb_i) / (sum_i exp(score_i))
__global__ __launch_bounds__(256, 4) void k_pool(
        const float* __restrict__ emb, const float* __restrict__ w_att,
        const int* __restrict__ base, const int* __restrict__ counts,
        const int* __restrict__ order, float* __restrict__ pooled, int S) {
    int wave = (blockIdx.x << 2) | (threadIdx.x >> 6);
    int lane = threadIdx.x & 63;
    if (wave >= S) return;
    int g   = lane >> 4;                    // element group 0..3
    int l16 = lane & 15;                    // lane within group
    int b   = base[wave];
    int cnt = counts[wave];
    const float* wrow = w_att + 8 * l16;
    float4 wa0 = *reinterpret_cast<const float4*>(wrow);
    float4 wa1 = *reinterpret_cast<const float4*>(wrow + 4);
    float4 a0 = make_float4(0.f, 0.f, 0.f, 0.f);
    float4 a1 = make_float4(0.f, 0.f, 0.f, 0.f);
    float Z = 0.f;
    if (cnt > 0) {
        int nit = (cnt + 3) >> 2;
        int e = g;
        int i0 = order[b + (e < cnt ? e : cnt - 1)];
        const float* r = emb + (size_t)i0 * 128 + 8 * l16;
        float4 v0 = *reinterpret_cast<const float4*>(r);
        float4 v1 = *reinterpret_cast<const float4*>(r + 4);
        for (int it = 0; it < nit; ++it) {
            int en = e + 4;
            // prefetch next group's row (clamped on the tail -> harmless dup)
            int inext = order[b + (en < cnt ? en : cnt - 1)];
            const float* rn = emb + (size_t)inext * 128 + 8 * l16;
            float4 n0 = *reinterpret_cast<const float4*>(rn);
            float4 n1 = *reinterpret_cast<const float4*>(rn + 4);
            // score for this group's element: 16-lane reduce (masks 1,2,4,8)
            float part = v0.x * wa0.x + v0.y * wa0.y + v0.z * wa0.z + v0.w * wa0.w
                       + v1.x * wa1.x + v1.y * wa1.y + v1.z * wa1.z + v1.w * wa1.w;
            part += __shfl_xor(part, 1);
            part += __shfl_xor(part, 2);
            part += __shfl_xor(part, 4);
            part += __shfl_xor(part, 8);
            float ex = (e < cnt) ? __expf(part) : 0.f;
            Z += ex;
            a0.x = fmaf(ex, v0.x, a0.x);
            a0.y = fmaf(ex, v0.y, a0.y);
            a0.z = fmaf(ex, v0.z, a0.z);
            a0.w = fmaf(ex, v0.w, a0.w);
            a1.x = fmaf(ex, v1.x, a1.x);
            a1.y = fmaf(ex, v1.y, a1.y);
            a1.z = fmaf(ex, v1.z, a1.z);
            a1.w = fmaf(ex, v1.w, a1.w);
            v0 = n0;
            v1 = n1;
            e = en;
        }
    }
    // combine the 4 groups (each lane set l16, l16+16, l16+32, l16+48 owns
    // the same dims)
#pragma unroll
    for (int m = 16; m <= 32; m <<= 1) {
        a0.x += __shfl_xor(a0.x, m);
        a0.y += __shfl_xor(a0.y, m);
        a0.z += __shfl_xor(a0.z, m);
        a0.w += __shfl_xor(a0.w, m);
        a1.x += __shfl_xor(a1.x, m);
        a1.y += __shfl_xor(a1.y, m);
        a1.z += __shfl_xor(a1.z, m);
        a1.w += __shfl_xor(a1.w, m);
        Z    += __shfl_xor(Z,    m);
    }
    float rn_ = (Z > 0.f) ? (1.0f / Z) : 0.f;
    if (g == 0) {
        float* o = pooled + (size_t)wave * 128 + 8 * l16;
        float4 o0 = make_float4(a0.x * rn_, a0.y * rn_, a0.z * rn_, a0.w * rn_);
        float4 o1 = make_float4(a1.x * rn_, a1.y * rn_, a1.z * rn_, a1.w * rn_);
        *reinterpret_cast<float4*>(o)     = o0;
        *reinterpret_cast<float4*>(o + 4) = o1;
    }
}

// ---------------- kernel 5: projection out = pooled @ w_out^T ---------------
// In-place on d_out: every block reads ALL its pooled rows (both k-halves)
// before storing any output row, and rows are block-exclusive -> safe.
#define SPB 8   // samples per block (compile-time so acc[] stays in registers)
__global__ __launch_bounds__(256, 4) void k_proj(
        const float* __restrict__ w_out, float* __restrict__ io, int S) {
    __shared__ float wl[128][68];           // half of w_out, pad 68 (16B-aligned rows)
    __shared__ float pl[2][64];
    int t = threadIdx.x;
    int d = t & 127;
    int h = t >> 7;
    int s0 = blockIdx.x * SPB;
    float acc[SPB / 2];
#pragma unroll
    for (int j = 0; j < SPB / 2; ++j) acc[j] = 0.f;

    for (int ph = 0; ph < 2; ++ph) {
        __syncthreads();                    // prev phase's reads of wl are done
        // stage w_out[:, ph*64 .. ph*64+63]  (8192 floats = 2048 float4)
        for (int j = t; j < 2048; j += 256) {
            int r  = j >> 4;
            int c4 = j & 15;
            float4 wv = reinterpret_cast<const float4*>(w_out + (size_t)r * 128 + ph * 64)[c4];
            wl[r][c4 * 4 + 0] = wv.x;
            wl[r][c4 * 4 + 1] = wv.y;
            wl[r][c4 * 4 + 2] = wv.z;
            wl[r][c4 * 4 + 3] = wv.w;
        }
        __syncthreads();
#pragma unroll
        for (int g = 0; g < SPB; g += 2) {
            if (t < 128) {
                int hh = t >> 6, kk = t & 63;
                int ss = s0 + g + hh;
                pl[hh][kk] = (ss < S) ? io[(size_t)ss * 128 + ph * 64 + kk] : 0.f;
            }
            __syncthreads();
            float a = 0.f;
#pragma unroll
            for (int k4 = 0; k4 < 16; ++k4) {
                float4 wv = *reinterpret_cast<const float4*>(&wl[d][k4 * 4]);
                float4 pv = *reinterpret_cast<const float4*>(&pl[h][k4 * 4]);
                a = fmaf(wv.x, pv.x, a);
                a = fmaf(wv.y, pv.y, a);
                a = fmaf(wv.z, pv.z, a);
                a = fmaf(wv.w, pv.w, a);
            }
            acc[g >> 1] += a;
            __syncthreads();                // pl reused next iteration
        }
    }
    // all pooled reads done by every thread in the block -> safe to overwrite
#pragma unroll
    for (int g = 0; g < SPB; g += 2) {
        int s = s0 + g + h;
        if (s < S) io[(size_t)s * 128 + d] = acc[g >> 1];
    }
}

extern "C" void kernel_launch(void* const* d_in, const int* in_sizes, int n_in,
                              void* d_out, int out_size, void* d_ws, size_t ws_size,
                              hipStream_t stream) {
    const float* emb   = (const float*)d_in[0];
    const float* w_att = (const float*)d_in[1];
    const float* w_out = (const float*)d_in[2];
    const int*   idx   = (const int*)d_in[3];
    const int N = in_sizes[0] / 128;
    const int S = out_size / 128;

    char* ws = (char*)d_ws;
    int* counts = (int*)(ws + 0);
    int* base   = (int*)(ws + 32 * 1024);
    int* cursor = (int*)(ws + 64 * 1024);
    int* order  = (int*)(ws + 128 * 1024);      // N ints
    float* out  = (float*)d_out;                // also holds pooled temporarily

    hipMemsetAsync(counts, 0, (size_t)S * sizeof(int), stream);
    k_hist   <<<(N + 255) / 256, 256, 0, stream>>>(idx, counts, N);
    k_scan   <<<1, 1024, 0, stream>>>(counts, base, cursor, S);
    k_scatter<<<(N + 255) / 256, 256, 0, stream>>>(idx, cursor, order, N);
    k_pool   <<<(S + 3) / 4, 256, 0, stream>>>(emb, w_att, base, counts, order, out, S);
    k_proj   <<<(S + SPB - 1) / SPB, 256, 0, stream>>>(w_out, out, S);
}